// Round 1
// baseline (83.559 us; speedup 1.0000x reference)
//
#include <hip/hip_runtime.h>

#define NQ  4
#define DIM 16

// ---------------------------------------------------------------------------
// Prep: simulate the 16 columns of the shared unitary U (RZ/RY layers + CNOT,
// two reps), then build A_o[j][k] = Re( sum_m conj(U[m][j]) * w_m(o) * U[m][k] )
// with w_m(o) = sum_i head_w[o,i] * (+1 if bit_i(m)==0 else -1).
// A (2 x 16 x 16 floats = 2 KB) goes to workspace.
// ---------------------------------------------------------------------------
__global__ __launch_bounds__(64) void prep_kernel(
    const float* __restrict__ weights,   // (2,4,4) flat; only [0,i,0:2] used
    const float* __restrict__ head_w,    // (2,4) flat
    float* __restrict__ A)               // 512 floats out
{
    __shared__ float Ure[DIM][DIM];      // U[m][j]
    __shared__ float Uim[DIM][DIM];
    const int j = threadIdx.x;
    if (j < DIM) {
        float sre[DIM], sim[DIM];
        #pragma unroll
        for (int m = 0; m < DIM; ++m) { sre[m] = (m == j) ? 1.f : 0.f; sim[m] = 0.f; }
        #pragma unroll
        for (int rep = 0; rep < 2; ++rep) {
            #pragma unroll
            for (int i = 0; i < NQ; ++i) {
                const float thz = weights[i * 4 + 0];
                const float thy = weights[i * 4 + 1];
                float sz, cz, sy, cy;
                sincosf(0.5f * thz, &sz, &cz);
                sincosf(0.5f * thy, &sy, &cy);
                const int bit = 8 >> i;   // wire i -> bit (wire 0 is MSB)
                #pragma unroll
                for (int m = 0; m < DIM; ++m) {
                    if (m & bit) continue;
                    const int m1 = m | bit;
                    const float are = sre[m],  aim = sim[m];
                    const float bre = sre[m1], bim = sim[m1];
                    // RZ: q=0 amp *= (cz - i sz); q=1 amp *= (cz + i sz)
                    const float n0re = are * cz + aim * sz;
                    const float n0im = aim * cz - are * sz;
                    const float n1re = bre * cz - bim * sz;
                    const float n1im = bim * cz + bre * sz;
                    // RY: new0 = cy*old0 - sy*old1 ; new1 = sy*old0 + cy*old1
                    sre[m]  = cy * n0re - sy * n1re;
                    sim[m]  = cy * n0im - sy * n1im;
                    sre[m1] = sy * n0re + cy * n1re;
                    sim[m1] = sy * n0im + cy * n1im;
                }
            }
            // CNOT(control = wire0 / bit8, target = wire1 / bit4):
            // swap q1 within the q0=1 half.
            #pragma unroll
            for (int m = 0; m < DIM; ++m) {
                if ((m & 8) && !(m & 4)) {
                    const int m2 = m | 4;
                    const float tr = sre[m], ti = sim[m];
                    sre[m] = sre[m2]; sim[m] = sim[m2];
                    sre[m2] = tr;     sim[m2] = ti;
                }
            }
        }
        #pragma unroll
        for (int m = 0; m < DIM; ++m) { Ure[m][j] = sre[m]; Uim[m][j] = sim[m]; }
    }
    __syncthreads();

    for (int idx = threadIdx.x; idx < 2 * DIM * DIM; idx += 64) {
        const int o  = idx >> 8;
        const int jj = (idx >> 4) & 15;
        const int kk = idx & 15;
        float acc = 0.f;
        for (int m = 0; m < DIM; ++m) {
            float w = 0.f;
            #pragma unroll
            for (int i = 0; i < NQ; ++i) {
                const float hw = head_w[o * 4 + i];
                w += ((m >> (3 - i)) & 1) ? -hw : hw;
            }
            acc += w * (Ure[m][jj] * Ure[m][kk] + Uim[m][jj] * Uim[m][kk]);
        }
        A[idx] = acc;
    }
}

// ---------------------------------------------------------------------------
// Main: one thread per sample. out[b,o] = psi^T A_o psi + head_b[o],
// psi = product state from the RY data-encoding layer (real).
// ---------------------------------------------------------------------------
__global__ __launch_bounds__(256) void qmain_kernel(
    const float* __restrict__ x,       // (B,4)
    const float* __restrict__ A,       // 512 floats (ws)
    const float* __restrict__ head_b,  // (2,)
    float* __restrict__ out,           // (B,2)
    const int Btot)
{
    __shared__ __align__(16) float sA[2 * DIM * DIM];
    __shared__ float sb[2];
    for (int i = threadIdx.x; i < 2 * DIM * DIM; i += 256) sA[i] = A[i];
    if (threadIdx.x < 2) sb[threadIdx.x] = head_b[threadIdx.x];
    __syncthreads();

    const int b = blockIdx.x * 256 + threadIdx.x;
    if (b >= Btot) return;

    const float4 xv = ((const float4*)x)[b];
    float c0, s0, c1, s1, c2, s2, c3, s3;
    __sincosf(0.5f * xv.x, &s0, &c0);
    __sincosf(0.5f * xv.y, &s1, &c1);
    __sincosf(0.5f * xv.z, &s2, &c2);
    __sincosf(0.5f * xv.w, &s3, &c3);

    float psi[DIM];
    {
        const float w0[2] = {c0, s0}, w1[2] = {c1, s1};
        const float w2[2] = {c2, s2}, w3[2] = {c3, s3};
        #pragma unroll
        for (int m = 0; m < DIM; ++m)
            psi[m] = w0[(m >> 3) & 1] * w1[(m >> 2) & 1] *
                     w2[(m >> 1) & 1] * w3[m & 1];
    }

    const float4* __restrict__ sA4 = (const float4*)sA;
    float r[2];
    #pragma unroll
    for (int o = 0; o < 2; ++o) {
        float acc = 0.f;
        #pragma unroll
        for (int jj = 0; jj < DIM; ++jj) {
            float mv = 0.f;
            #pragma unroll
            for (int kq = 0; kq < 4; ++kq) {
                const float4 a4 = sA4[(o * DIM + jj) * 4 + kq];
                mv = fmaf(a4.x, psi[kq * 4 + 0], mv);
                mv = fmaf(a4.y, psi[kq * 4 + 1], mv);
                mv = fmaf(a4.z, psi[kq * 4 + 2], mv);
                mv = fmaf(a4.w, psi[kq * 4 + 3], mv);
            }
            acc = fmaf(psi[jj], mv, acc);
        }
        r[o] = acc + sb[o];
    }
    ((float2*)out)[b] = make_float2(r[0], r[1]);
}

extern "C" void kernel_launch(void* const* d_in, const int* in_sizes, int n_in,
                              void* d_out, int out_size, void* d_ws, size_t ws_size,
                              hipStream_t stream) {
    const float* x       = (const float*)d_in[0];   // (B,4)
    const float* weights = (const float*)d_in[1];   // (2,4,4)
    const float* head_w  = (const float*)d_in[2];   // (2,4)
    const float* head_b  = (const float*)d_in[3];   // (2,)
    float* out = (float*)d_out;
    float* A   = (float*)d_ws;                      // 512 floats

    const int Btot = in_sizes[0] / 4;

    prep_kernel<<<1, 64, 0, stream>>>(weights, head_w, A);
    const int blocks = (Btot + 255) / 256;
    qmain_kernel<<<blocks, 256, 0, stream>>>(x, A, head_b, out, Btot);
}

// Round 2
// 75.516 us; speedup vs baseline: 1.1065x; 1.1065x over previous
//
#include <hip/hip_runtime.h>

#define NQ  4
#define DIM 16

// ---------------------------------------------------------------------------
// Prep (1 block, 64 threads):
//   1) simulate the 16 columns of the shared unitary U (RZ/RY x2 + CNOT01)
//   2) A_o[j][k] = sum_m w_m(o) * Re(conj(U[m][j]) U[m][k]),
//      w_m(o) = sum_i head_w[o,i] * (bit_i(m) ? -1 : +1)
//   3) basis change to the (1, cos x, sin x) product basis:
//      T[o][a0,a1,a2,a3] = (1/16) * sum_{j=0..15} sign(j,a) * A_o[j][j^m(a)]
//      where m(a) has bit(3-i) set iff a_i==2, sign flips per bit where a_i==1.
//      head_b folded into T[o][0].
//   T = 162 floats -> d_ws.
// ---------------------------------------------------------------------------
__global__ __launch_bounds__(64) void prep_kernel(
    const float* __restrict__ weights,   // (2,4,4) flat; only [0,i,0:2] used
    const float* __restrict__ head_w,    // (2,4)
    const float* __restrict__ head_b,    // (2,)
    float* __restrict__ T)               // 162 floats out
{
    __shared__ float Ure[DIM][DIM];      // U[m][j]
    __shared__ float Uim[DIM][DIM];
    __shared__ float sA[2][DIM][DIM];

    const int j = threadIdx.x;
    if (j < DIM) {
        float sre[DIM], sim[DIM];
        #pragma unroll
        for (int m = 0; m < DIM; ++m) { sre[m] = (m == j) ? 1.f : 0.f; sim[m] = 0.f; }
        #pragma unroll
        for (int rep = 0; rep < 2; ++rep) {
            #pragma unroll
            for (int i = 0; i < NQ; ++i) {
                const float thz = weights[i * 4 + 0];
                const float thy = weights[i * 4 + 1];
                float sz, cz, sy, cy;
                sincosf(0.5f * thz, &sz, &cz);
                sincosf(0.5f * thy, &sy, &cy);
                const int bit = 8 >> i;   // wire i -> bit (wire 0 is MSB)
                #pragma unroll
                for (int m = 0; m < DIM; ++m) {
                    if (m & bit) continue;
                    const int m1 = m | bit;
                    const float are = sre[m],  aim = sim[m];
                    const float bre = sre[m1], bim = sim[m1];
                    // RZ
                    const float n0re = are * cz + aim * sz;
                    const float n0im = aim * cz - are * sz;
                    const float n1re = bre * cz - bim * sz;
                    const float n1im = bim * cz + bre * sz;
                    // RY
                    sre[m]  = cy * n0re - sy * n1re;
                    sim[m]  = cy * n0im - sy * n1im;
                    sre[m1] = sy * n0re + cy * n1re;
                    sim[m1] = sy * n0im + cy * n1im;
                }
            }
            // CNOT(wire0 -> wire1): swap bit4 halves within bit8=1
            #pragma unroll
            for (int m = 0; m < DIM; ++m) {
                if ((m & 8) && !(m & 4)) {
                    const int m2 = m | 4;
                    const float tr = sre[m], ti = sim[m];
                    sre[m] = sre[m2]; sim[m] = sim[m2];
                    sre[m2] = tr;     sim[m2] = ti;
                }
            }
        }
        #pragma unroll
        for (int m = 0; m < DIM; ++m) { Ure[m][j] = sre[m]; Uim[m][j] = sim[m]; }
    }
    __syncthreads();

    // Stage 2: A (512 entries over 64 threads)
    for (int idx = threadIdx.x; idx < 2 * DIM * DIM; idx += 64) {
        const int o  = idx >> 8;
        const int jj = (idx >> 4) & 15;
        const int kk = idx & 15;
        float acc = 0.f;
        for (int m = 0; m < DIM; ++m) {
            float w = 0.f;
            #pragma unroll
            for (int i = 0; i < NQ; ++i) {
                const float hw = head_w[o * 4 + i];
                w += ((m >> (3 - i)) & 1) ? -hw : hw;
            }
            acc += w * (Ure[m][jj] * Ure[m][kk] + Uim[m][jj] * Uim[m][kk]);
        }
        sA[o][jj][kk] = acc;
    }
    __syncthreads();

    // Stage 3: T (162 entries over 64 threads); 16 signed terms each
    for (int idx = threadIdx.x; idx < 2 * 81; idx += 64) {
        const int o  = idx / 81;
        const int r  = idx % 81;
        const int a0 = r / 27, a1 = (r / 9) % 3, a2 = (r / 3) % 3, a3 = r % 3;
        const int xm = ((a0 == 2) << 3) | ((a1 == 2) << 2) | ((a2 == 2) << 1) | (a3 == 2);
        const int sm = ((a0 == 1) << 3) | ((a1 == 1) << 2) | ((a2 == 1) << 1) | (a3 == 1);
        float acc = 0.f;
        #pragma unroll
        for (int jj = 0; jj < DIM; ++jj) {
            const float s = (__popc(jj & sm) & 1) ? -1.f : 1.f;
            acc += s * sA[o][jj][jj ^ xm];
        }
        float t = acc * 0.0625f;
        if (r == 0) t += head_b[o];
        T[idx] = t;
    }
}

// ---------------------------------------------------------------------------
// Main: one thread per sample; no LDS. T reads are compile-time-uniform
// addresses from a read-only pointer -> SMEM (s_load), SGPR operands to FMA.
//   out[b,o] = sum_{a0} v0[a0] * sum_{j=0..26} T[o][a0][j] * u[j]
//   u = v1 (x) v2 (x) v3,  v_i = (1, cos x_i, sin x_i)
// ---------------------------------------------------------------------------
template <bool CHK>
__global__ __launch_bounds__(256) void qmain_kernel(
    const float4* __restrict__ x4,     // (B) of float4
    const float* __restrict__ T,       // 162 floats (ws)
    float2* __restrict__ out,          // (B)
    const int Btot)
{
    const int b = blockIdx.x * 256 + threadIdx.x;
    if (CHK && b >= Btot) return;

    const float4 xv = x4[b];
    float c0, s0, c1, s1, c2, s2, c3, s3;
    __sincosf(xv.x, &s0, &c0);
    __sincosf(xv.y, &s1, &c1);
    __sincosf(xv.z, &s2, &c2);
    __sincosf(xv.w, &s3, &c3);

    const float v0[3] = {1.f, c0, s0};
    const float v1[3] = {1.f, c1, s1};
    const float v2[3] = {1.f, c2, s2};
    const float v3[3] = {1.f, c3, s3};

    float u[27];
    #pragma unroll
    for (int a = 0; a < 3; ++a) {
        #pragma unroll
        for (int bq = 0; bq < 3; ++bq) {
            const float vv = v1[a] * v2[bq];
            #pragma unroll
            for (int cq = 0; cq < 3; ++cq)
                u[a * 9 + bq * 3 + cq] = vv * v3[cq];
        }
    }

    float r[2];
    #pragma unroll
    for (int o = 0; o < 2; ++o) {
        float acc = 0.f;
        #pragma unroll
        for (int a0 = 0; a0 < 3; ++a0) {
            float d = 0.f;
            #pragma unroll
            for (int jj = 0; jj < 27; ++jj)
                d = fmaf(T[o * 81 + a0 * 27 + jj], u[jj], d);
            acc = fmaf(v0[a0], d, acc);
        }
        r[o] = acc;
    }
    out[b] = make_float2(r[0], r[1]);
}

extern "C" void kernel_launch(void* const* d_in, const int* in_sizes, int n_in,
                              void* d_out, int out_size, void* d_ws, size_t ws_size,
                              hipStream_t stream) {
    const float* x       = (const float*)d_in[0];   // (B,4)
    const float* weights = (const float*)d_in[1];   // (2,4,4)
    const float* head_w  = (const float*)d_in[2];   // (2,4)
    const float* head_b  = (const float*)d_in[3];   // (2,)
    float* out = (float*)d_out;
    float* T   = (float*)d_ws;                      // 162 floats

    const int Btot = in_sizes[0] / 4;

    prep_kernel<<<1, 64, 0, stream>>>(weights, head_w, head_b, T);

    if ((Btot & 255) == 0) {
        qmain_kernel<false><<<Btot / 256, 256, 0, stream>>>(
            (const float4*)x, T, (float2*)out, Btot);
    } else {
        qmain_kernel<true><<<(Btot + 255) / 256, 256, 0, stream>>>(
            (const float4*)x, T, (float2*)out, Btot);
    }
}

// Round 3
// 71.421 us; speedup vs baseline: 1.1699x; 1.0573x over previous
//
#include <hip/hip_runtime.h>

#define NQ  4
#define DIM 16

// ---------------------------------------------------------------------------
// Prep (1 block, 64 threads):
//   1) simulate the 16 columns of the shared unitary U (RZ/RY x2 + CNOT01)
//   2) A_o[j][k] = sum_m w_m(o) * Re(conj(U[m][j]) U[m][k]),
//      w_m(o) = sum_i head_w[o,i] * (bit_i(m) ? -1 : +1)
//   3) basis change to the (1, cos x, sin x) product basis:
//      T[o][a0,a1,a2,a3] = (1/16) * sum_j sign(j,a) * A_o[j][j^m(a)]
//      head_b folded into T[o][0].  T = 162 floats -> d_ws.
// Angles are identical across the two reps (only weights[0,i,0:2] used),
// so the 8 sincos are hoisted out of the rep loop; __sincosf (HW sin/cos)
// is accurate to ~1e-6 for |theta/2| < pi, fine vs the 2.8e-2 threshold.
// ---------------------------------------------------------------------------
__global__ __launch_bounds__(64) void prep_kernel(
    const float* __restrict__ weights,   // (2,4,4) flat; only [0,i,0:2] used
    const float* __restrict__ head_w,    // (2,4)
    const float* __restrict__ head_b,    // (2,)
    float* __restrict__ T)               // 162 floats out
{
    __shared__ float Ure[DIM][DIM];      // U[m][j]
    __shared__ float Uim[DIM][DIM];
    __shared__ float sA[2][DIM][DIM];

    const int j = threadIdx.x;
    if (j < DIM) {
        float szv[NQ], czv[NQ], syv[NQ], cyv[NQ];
        #pragma unroll
        for (int i = 0; i < NQ; ++i) {
            __sincosf(0.5f * weights[i * 4 + 0], &szv[i], &czv[i]);
            __sincosf(0.5f * weights[i * 4 + 1], &syv[i], &cyv[i]);
        }
        float sre[DIM], sim[DIM];
        #pragma unroll
        for (int m = 0; m < DIM; ++m) { sre[m] = (m == j) ? 1.f : 0.f; sim[m] = 0.f; }
        #pragma unroll
        for (int rep = 0; rep < 2; ++rep) {
            #pragma unroll
            for (int i = 0; i < NQ; ++i) {
                const float sz = szv[i], cz = czv[i];
                const float sy = syv[i], cy = cyv[i];
                const int bit = 8 >> i;   // wire i -> bit (wire 0 is MSB)
                #pragma unroll
                for (int m = 0; m < DIM; ++m) {
                    if (m & bit) continue;
                    const int m1 = m | bit;
                    const float are = sre[m],  aim = sim[m];
                    const float bre = sre[m1], bim = sim[m1];
                    // RZ
                    const float n0re = are * cz + aim * sz;
                    const float n0im = aim * cz - are * sz;
                    const float n1re = bre * cz - bim * sz;
                    const float n1im = bim * cz + bre * sz;
                    // RY
                    sre[m]  = cy * n0re - sy * n1re;
                    sim[m]  = cy * n0im - sy * n1im;
                    sre[m1] = sy * n0re + cy * n1re;
                    sim[m1] = sy * n0im + cy * n1im;
                }
            }
            // CNOT(wire0 -> wire1): swap bit4 halves within bit8=1
            #pragma unroll
            for (int m = 0; m < DIM; ++m) {
                if ((m & 8) && !(m & 4)) {
                    const int m2 = m | 4;
                    const float tr = sre[m], ti = sim[m];
                    sre[m] = sre[m2]; sim[m] = sim[m2];
                    sre[m2] = tr;     sim[m2] = ti;
                }
            }
        }
        #pragma unroll
        for (int m = 0; m < DIM; ++m) { Ure[m][j] = sre[m]; Uim[m][j] = sim[m]; }
    }
    __syncthreads();

    // Stage 2: A (512 entries over 64 threads)
    for (int idx = threadIdx.x; idx < 2 * DIM * DIM; idx += 64) {
        const int o  = idx >> 8;
        const int jj = (idx >> 4) & 15;
        const int kk = idx & 15;
        float acc = 0.f;
        for (int m = 0; m < DIM; ++m) {
            float w = 0.f;
            #pragma unroll
            for (int i = 0; i < NQ; ++i) {
                const float hw = head_w[o * 4 + i];
                w += ((m >> (3 - i)) & 1) ? -hw : hw;
            }
            acc += w * (Ure[m][jj] * Ure[m][kk] + Uim[m][jj] * Uim[m][kk]);
        }
        sA[o][jj][kk] = acc;
    }
    __syncthreads();

    // Stage 3: T (162 entries over 64 threads); 16 signed terms each
    for (int idx = threadIdx.x; idx < 2 * 81; idx += 64) {
        const int o  = idx / 81;
        const int r  = idx % 81;
        const int a0 = r / 27, a1 = (r / 9) % 3, a2 = (r / 3) % 3, a3 = r % 3;
        const int xm = ((a0 == 2) << 3) | ((a1 == 2) << 2) | ((a2 == 2) << 1) | (a3 == 2);
        const int sm = ((a0 == 1) << 3) | ((a1 == 1) << 2) | ((a2 == 1) << 1) | (a3 == 1);
        float acc = 0.f;
        #pragma unroll
        for (int jj = 0; jj < DIM; ++jj) {
            const float s = (__popc(jj & sm) & 1) ? -1.f : 1.f;
            acc += s * sA[o][jj][jj ^ xm];
        }
        float t = acc * 0.0625f;
        if (r == 0) t += head_b[o];
        T[idx] = t;
    }
}

// ---------------------------------------------------------------------------
// Main: 2 samples per thread; no LDS. T reads are uniform addresses from a
// const __restrict__ kernel arg -> s_load (SMEM), SGPR operands to the FMAs.
//   out[b,o] = sum_{a0} v0[a0] * sum_{j} T[o][a0][j] * u[j]
//   u = v1 (x) v2 (x) v3,  v_i = (1, cos x_i, sin x_i)
// ---------------------------------------------------------------------------
__device__ __forceinline__ float2 qeval(const float4 xv, const float* __restrict__ T)
{
    float c0, s0, c1, s1, c2, s2, c3, s3;
    __sincosf(xv.x, &s0, &c0);
    __sincosf(xv.y, &s1, &c1);
    __sincosf(xv.z, &s2, &c2);
    __sincosf(xv.w, &s3, &c3);

    const float v0[3] = {1.f, c0, s0};
    const float v1[3] = {1.f, c1, s1};
    const float v2[3] = {1.f, c2, s2};
    const float v3[3] = {1.f, c3, s3};

    float u[27];
    #pragma unroll
    for (int a = 0; a < 3; ++a) {
        #pragma unroll
        for (int bq = 0; bq < 3; ++bq) {
            const float vv = v1[a] * v2[bq];
            #pragma unroll
            for (int cq = 0; cq < 3; ++cq)
                u[a * 9 + bq * 3 + cq] = vv * v3[cq];
        }
    }

    float r[2];
    #pragma unroll
    for (int o = 0; o < 2; ++o) {
        float acc = 0.f;
        #pragma unroll
        for (int a0 = 0; a0 < 3; ++a0) {
            float d = 0.f;
            #pragma unroll
            for (int jj = 0; jj < 27; ++jj)
                d = fmaf(T[o * 81 + a0 * 27 + jj], u[jj], d);
            acc = fmaf(v0[a0], d, acc);
        }
        r[o] = acc;
    }
    return make_float2(r[0], r[1]);
}

// 2 samples/thread, float4 (16B) stores
__global__ __launch_bounds__(256) void qmain2_kernel(
    const float4* __restrict__ x4,     // (B) of float4
    const float* __restrict__ T,       // 162 floats (ws)
    float4* __restrict__ out4)         // (B/2) of float4
{
    const int t = blockIdx.x * 256 + threadIdx.x;
    const float4 xa = x4[2 * t];
    const float4 xb = x4[2 * t + 1];
    const float2 ra = qeval(xa, T);
    const float2 rb = qeval(xb, T);
    out4[t] = make_float4(ra.x, ra.y, rb.x, rb.y);
}

// fallback: 1 sample/thread with bounds check
__global__ __launch_bounds__(256) void qmain1_kernel(
    const float4* __restrict__ x4,
    const float* __restrict__ T,
    float2* __restrict__ out,
    const int Btot)
{
    const int b = blockIdx.x * 256 + threadIdx.x;
    if (b >= Btot) return;
    out[b] = qeval(x4[b], T);
}

extern "C" void kernel_launch(void* const* d_in, const int* in_sizes, int n_in,
                              void* d_out, int out_size, void* d_ws, size_t ws_size,
                              hipStream_t stream) {
    const float* x       = (const float*)d_in[0];   // (B,4)
    const float* weights = (const float*)d_in[1];   // (2,4,4)
    const float* head_w  = (const float*)d_in[2];   // (2,4)
    const float* head_b  = (const float*)d_in[3];   // (2,)
    float* out = (float*)d_out;
    float* T   = (float*)d_ws;                      // 162 floats

    const int Btot = in_sizes[0] / 4;

    prep_kernel<<<1, 64, 0, stream>>>(weights, head_w, head_b, T);

    if ((Btot & 511) == 0) {
        qmain2_kernel<<<Btot / 512, 256, 0, stream>>>(
            (const float4*)x, T, (float4*)out);
    } else {
        qmain1_kernel<<<(Btot + 255) / 256, 256, 0, stream>>>(
            (const float4*)x, T, (float2*)out, Btot);
    }
}

// Round 4
// 70.861 us; speedup vs baseline: 1.1792x; 1.0079x over previous
//
#include <hip/hip_runtime.h>

#define NQ  4
#define DIM 16

// ---------------------------------------------------------------------------
// Prep (1 block, 256 threads):
//   1) [threads 0..15] simulate the 16 columns of the shared unitary U
//      (RZ/RY x2 + CNOT01); angles identical across reps -> 8 sincos hoisted.
//   2) [threads 0..31] w[o][m] = sum_i head_w[o,i] * (bit_i(m) ? -1 : +1)
//   3) [all 256] A_o[j][k] = sum_m w[o][m] * Re(conj(U[m][j]) U[m][k])
//   4) [threads 0..161] basis change to the (1, cos x, sin x) product basis:
//      T[o][a0,a1,a2,a3] = (1/16) * sum_j sign(j,a) * A_o[j][j^m(a)]
//      head_b folded into T[o][0].  T = 162 floats -> d_ws.
// ---------------------------------------------------------------------------
__global__ __launch_bounds__(256) void prep_kernel(
    const float* __restrict__ weights,   // (2,4,4) flat; only [0,i,0:2] used
    const float* __restrict__ head_w,    // (2,4)
    const float* __restrict__ head_b,    // (2,)
    float* __restrict__ T)               // 162 floats out
{
    __shared__ float Ure[DIM][DIM];      // U[m][j]
    __shared__ float Uim[DIM][DIM];
    __shared__ float sw[2][DIM];         // w[o][m]
    __shared__ float sA[2][DIM][DIM];

    const int tid = threadIdx.x;

    if (tid < DIM) {
        const int j = tid;
        float szv[NQ], czv[NQ], syv[NQ], cyv[NQ];
        #pragma unroll
        for (int i = 0; i < NQ; ++i) {
            __sincosf(0.5f * weights[i * 4 + 0], &szv[i], &czv[i]);
            __sincosf(0.5f * weights[i * 4 + 1], &syv[i], &cyv[i]);
        }
        float sre[DIM], sim[DIM];
        #pragma unroll
        for (int m = 0; m < DIM; ++m) { sre[m] = (m == j) ? 1.f : 0.f; sim[m] = 0.f; }
        #pragma unroll
        for (int rep = 0; rep < 2; ++rep) {
            #pragma unroll
            for (int i = 0; i < NQ; ++i) {
                const float sz = szv[i], cz = czv[i];
                const float sy = syv[i], cy = cyv[i];
                const int bit = 8 >> i;   // wire i -> bit (wire 0 is MSB)
                #pragma unroll
                for (int m = 0; m < DIM; ++m) {
                    if (m & bit) continue;
                    const int m1 = m | bit;
                    const float are = sre[m],  aim = sim[m];
                    const float bre = sre[m1], bim = sim[m1];
                    // RZ
                    const float n0re = are * cz + aim * sz;
                    const float n0im = aim * cz - are * sz;
                    const float n1re = bre * cz - bim * sz;
                    const float n1im = bim * cz + bre * sz;
                    // RY
                    sre[m]  = cy * n0re - sy * n1re;
                    sim[m]  = cy * n0im - sy * n1im;
                    sre[m1] = sy * n0re + cy * n1re;
                    sim[m1] = sy * n0im + cy * n1im;
                }
            }
            // CNOT(wire0 -> wire1): swap bit4 halves within bit8=1
            #pragma unroll
            for (int m = 0; m < DIM; ++m) {
                if ((m & 8) && !(m & 4)) {
                    const int m2 = m | 4;
                    const float tr = sre[m], ti = sim[m];
                    sre[m] = sre[m2]; sim[m] = sim[m2];
                    sre[m2] = tr;     sim[m2] = ti;
                }
            }
        }
        #pragma unroll
        for (int m = 0; m < DIM; ++m) { Ure[m][j] = sre[m]; Uim[m][j] = sim[m]; }
    } else if (tid < DIM + 32) {
        // w[o][m], 32 entries
        const int t = tid - DIM;
        const int o = t >> 4, m = t & 15;
        float w = 0.f;
        #pragma unroll
        for (int i = 0; i < NQ; ++i) {
            const float hw = head_w[o * 4 + i];
            w += ((m >> (3 - i)) & 1) ? -hw : hw;
        }
        sw[o][m] = w;
    }
    __syncthreads();

    // Stage 3: A (512 entries over 256 threads, 2 iterations)
    #pragma unroll
    for (int it = 0; it < 2; ++it) {
        const int idx = it * 256 + tid;
        const int o  = idx >> 8;
        const int jj = (idx >> 4) & 15;
        const int kk = idx & 15;
        float acc = 0.f;
        #pragma unroll
        for (int m = 0; m < DIM; ++m)
            acc = fmaf(sw[o][m],
                       Ure[m][jj] * Ure[m][kk] + Uim[m][jj] * Uim[m][kk], acc);
        sA[o][jj][kk] = acc;
    }
    __syncthreads();

    // Stage 4: T (162 entries, one pass)
    if (tid < 2 * 81) {
        const int o  = tid / 81;
        const int r  = tid % 81;
        const int a0 = r / 27, a1 = (r / 9) % 3, a2 = (r / 3) % 3, a3 = r % 3;
        const int xm = ((a0 == 2) << 3) | ((a1 == 2) << 2) | ((a2 == 2) << 1) | (a3 == 2);
        const int sm = ((a0 == 1) << 3) | ((a1 == 1) << 2) | ((a2 == 1) << 1) | (a3 == 1);
        float acc = 0.f;
        #pragma unroll
        for (int jj = 0; jj < DIM; ++jj) {
            const float s = (__popc(jj & sm) & 1) ? -1.f : 1.f;
            acc += s * sA[o][jj][jj ^ xm];
        }
        float t = acc * 0.0625f;
        if (r == 0) t += head_b[o];
        T[tid] = t;
    }
}

// ---------------------------------------------------------------------------
// Main: 2 samples per thread; no LDS. T reads are uniform addresses from a
// const __restrict__ kernel arg -> s_load (SMEM), SGPR operands to the FMAs.
// Sequential mode contraction (a3 -> a2 -> a1 -> a0), 80 FMA per output:
//   w3[t] = T[3t] + c3*T[3t+1] + s3*T[3t+2]   (27 entries)
//   w2[t] = w3[3t] + c2*w3[3t+1] + s2*w3[3t+2] (9)
//   w1[t] = ...(3);  r = w1[0] + c0*w1[1] + s0*w1[2]
// ---------------------------------------------------------------------------
__device__ __forceinline__ float2 qeval(const float4 xv, const float* __restrict__ T)
{
    float c0, s0, c1, s1, c2, s2, c3, s3;
    __sincosf(xv.x, &s0, &c0);
    __sincosf(xv.y, &s1, &c1);
    __sincosf(xv.z, &s2, &c2);
    __sincosf(xv.w, &s3, &c3);

    float r[2];
    #pragma unroll
    for (int o = 0; o < 2; ++o) {
        float w2[9];
        #pragma unroll
        for (int t = 0; t < 9; ++t) {
            float a = fmaf(s3, T[o * 81 + 9 * t + 2], fmaf(c3, T[o * 81 + 9 * t + 1], T[o * 81 + 9 * t + 0]));
            // NOTE: layout is [a0][a1][a2][a3], a3 stride 1; t enumerates (a0,a1,a2)
            // contiguous groups of 3 -> base = 3*t... fixed below.
            w2[t] = a;
        }
        // The above used wrong stride; recompute correctly:
        float w3[27];
        #pragma unroll
        for (int t = 0; t < 27; ++t)
            w3[t] = fmaf(s3, T[o * 81 + 3 * t + 2],
                    fmaf(c3, T[o * 81 + 3 * t + 1], T[o * 81 + 3 * t + 0]));
        #pragma unroll
        for (int t = 0; t < 9; ++t)
            w2[t] = fmaf(s2, w3[3 * t + 2], fmaf(c2, w3[3 * t + 1], w3[3 * t + 0]));
        float w1[3];
        #pragma unroll
        for (int t = 0; t < 3; ++t)
            w1[t] = fmaf(s1, w2[3 * t + 2], fmaf(c1, w2[3 * t + 1], w2[3 * t + 0]));
        r[o] = fmaf(s0, w1[2], fmaf(c0, w1[1], w1[0]));
    }
    return make_float2(r[0], r[1]);
}

// 2 samples/thread, float4 (16B) stores
__global__ __launch_bounds__(256) void qmain2_kernel(
    const float4* __restrict__ x4,     // (B) of float4
    const float* __restrict__ T,       // 162 floats (ws)
    float4* __restrict__ out4)         // (B/2) of float4
{
    const int t = blockIdx.x * 256 + threadIdx.x;
    const float4 xa = x4[2 * t];
    const float4 xb = x4[2 * t + 1];
    const float2 ra = qeval(xa, T);
    const float2 rb = qeval(xb, T);
    out4[t] = make_float4(ra.x, ra.y, rb.x, rb.y);
}

// fallback: 1 sample/thread with bounds check
__global__ __launch_bounds__(256) void qmain1_kernel(
    const float4* __restrict__ x4,
    const float* __restrict__ T,
    float2* __restrict__ out,
    const int Btot)
{
    const int b = blockIdx.x * 256 + threadIdx.x;
    if (b >= Btot) return;
    out[b] = qeval(x4[b], T);
}

extern "C" void kernel_launch(void* const* d_in, const int* in_sizes, int n_in,
                              void* d_out, int out_size, void* d_ws, size_t ws_size,
                              hipStream_t stream) {
    const float* x       = (const float*)d_in[0];   // (B,4)
    const float* weights = (const float*)d_in[1];   // (2,4,4)
    const float* head_w  = (const float*)d_in[2];   // (2,4)
    const float* head_b  = (const float*)d_in[3];   // (2,)
    float* out = (float*)d_out;
    float* T   = (float*)d_ws;                      // 162 floats

    const int Btot = in_sizes[0] / 4;

    prep_kernel<<<1, 256, 0, stream>>>(weights, head_w, head_b, T);

    if ((Btot & 511) == 0) {
        qmain2_kernel<<<Btot / 512, 256, 0, stream>>>(
            (const float4*)x, T, (float4*)out);
    } else {
        qmain1_kernel<<<(Btot + 255) / 256, 256, 0, stream>>>(
            (const float4*)x, T, (float2*)out, Btot);
    }
}